// Round 6
// baseline (403.021 us; speedup 1.0000x reference)
//
#include <hip/hip_runtime.h>
#include <math.h>

// Problem constants (B=1)
#define MM 1024
#define DD 512
#define CC 128
#define LDSR 520   // A row stride in ushorts: 1040 B (16B-aligned rows -> ds_read_b128).
                   // Row-to-row bank shift: 260 dw ≡ 4 (mod 32); a wave's 64 b128 reads
                   // spread uniformly 8 accesses/bank = conflict-minimal.

// ws layout (floats):
//  H[1024][3072]      @ 0        (0..1023 ms-hidden, 1024.. src_proj, 2048.. ant_proj)
//  slow0[1024][128]   @ 3145728  (fh=0 partials)
//  spk_proj[2][1024]  @ 3276800
//  bkt_proj[10][1024] @ 3278848
//  ms[1024]           @ 3289088
//  lossp[1024]        @ 3290112
//  embb bf16[1024][512]  @ 3291136
//  Wall bf16[4096][512]  @ 3553280
//    rows [0,1024)=ms_W0^T, [1024,2048)=W_src^T, [2048,3072)=W_ant^T
//    region [3072,4096) reused as Wfrag: [tile t:32][kstep s:32][lane:64][8] bf16
//      element (f = t*32 + (lane&31), k = s*16 + (lane>>5)*8 + j) at ((t*32+s)*64+lane)*8+j
//  slow1[1024][128]   @ 4601856  (fh=1 partials)

typedef __attribute__((ext_vector_type(8))) short bf16x8;
typedef __attribute__((ext_vector_type(4))) float f32x4;
typedef __attribute__((ext_vector_type(16))) float f32x16;

__device__ __forceinline__ ushort bf16_rn(float x) {
    uint u = __float_as_uint(x);
    uint r = u + 0x7fffu + ((u >> 16) & 1u);
    return (ushort)(r >> 16);
}
__device__ __forceinline__ float bf16_to_f(ushort u) {
    return __uint_as_float(((uint)u) << 16);
}
__device__ __forceinline__ bf16x8 ld_lds16(const ushort* p) {   // one ds_read_b128 (16B-aligned)
    return *(const bf16x8*)__builtin_assume_aligned(p, 16);
}

// ---------------- prep: emb fp32 -> bf16
__global__ __launch_bounds__(256) void prep_emb(const float* __restrict__ emb,
                                                ushort* __restrict__ embb)
{
    int i = blockIdx.x * 256 + threadIdx.x;
    float2 v = ((const float2*)emb)[i];
    ushort2 o;
    o.x = bf16_rn(v.x);
    o.y = bf16_rn(v.y);
    ((ushort2*)embb)[i] = o;
}

// ---------------- prep: transpose+convert W0 blocks 0..2 -> Wall[3072 n][512 k] bf16
__global__ __launch_bounds__(256) void prep_wall(const float* __restrict__ ms_W0,
                                                 const float* __restrict__ sp_W0,
                                                 ushort* __restrict__ Wall)
{
    __shared__ float t[64][65];
    const int k0 = blockIdx.x * 64;   // 8
    const int n0 = blockIdx.y * 64;   // 48
    const int g = n0 >> 10;
    const float* src = (g == 0) ? ms_W0 : (sp_W0 + (size_t)(g - 1) * 512 * 1024);
    const int col0 = n0 & 1023;
    const int tr = threadIdx.x >> 6, tc = threadIdx.x & 63;
#pragma unroll
    for (int i = 0; i < 16; ++i) {
        int k = tr + i * 4;
        t[k][tc] = src[(size_t)(k0 + k) * 1024 + col0 + tc];
    }
    __syncthreads();
    const int f = threadIdx.x >> 2;
    const int c4 = threadIdx.x & 3;
    ushort tmp[16];
#pragma unroll
    for (int j = 0; j < 16; ++j) tmp[j] = bf16_rn(t[c4 * 16 + j][f]);
    uint4* dst = (uint4*)(Wall + (size_t)(n0 + f) * 512 + k0 + c4 * 16);
    dst[0] = *(uint4*)&tmp[0];
    dst[1] = *(uint4*)&tmp[8];
}

// ---------------- prep: W [k=512][f=1024] -> fragment-major (wave load = contiguous 1 KB)
__global__ __launch_bounds__(64) void prep_wfrag(const float* __restrict__ W,
                                                 ushort* __restrict__ dst_frag)
{
    const int ts = blockIdx.x;            // t*32 + s, 0..1023
    const int l = threadIdx.x;            // 0..63
    const int tt = ts >> 5, s = ts & 31;
    const int f = tt * 32 + (l & 31);
    const int kb = s * 16 + (l >> 5) * 8;
    ushort tmp[8];
#pragma unroll
    for (int j = 0; j < 8; ++j) tmp[j] = bf16_rn(W[(size_t)(kb + j) * 1024 + f]);
    uint4* dst = (uint4*)(dst_frag + ((size_t)ts * 64 + l) * 8);
    *dst = *(uint4*)&tmp[0];
}

// ---------------- H = emb @ [ms_W0 | W_src | W_ant] via MFMA (1024x512x3072)
__global__ __launch_bounds__(256) void gemm_h_mfma(
    const ushort* __restrict__ embb, const ushort* __restrict__ Wall,
    float* __restrict__ H)
{
    const int n0 = blockIdx.x * 128;  // 24
    const int m0 = blockIdx.y * 128;  // 8
    const int lane = threadIdx.x & 63, wave = threadIdx.x >> 6;
    const int wx = wave & 1, wy = wave >> 1;
    const int l15 = lane & 15, lq = lane >> 4;

    const ushort* arow[4];
#pragma unroll
    for (int mi = 0; mi < 4; ++mi)
        arow[mi] = embb + (size_t)(m0 + wy * 64 + mi * 16 + l15) * 512;
    const ushort* brow[4];
#pragma unroll
    for (int ni = 0; ni < 4; ++ni)
        brow[ni] = Wall + (size_t)(n0 + wx * 64 + ni * 16 + l15) * 512;

    f32x4 acc[4][4];
#pragma unroll
    for (int i = 0; i < 4; ++i)
#pragma unroll
        for (int j = 0; j < 4; ++j) acc[i][j] = (f32x4)0.f;

    for (int kt = 0; kt < 512; kt += 32) {
        const int ko = kt + lq * 8;
        bf16x8 av[4], bv[4];
#pragma unroll
        for (int mi = 0; mi < 4; ++mi) av[mi] = *(const bf16x8*)(arow[mi] + ko);
#pragma unroll
        for (int ni = 0; ni < 4; ++ni) bv[ni] = *(const bf16x8*)(brow[ni] + ko);
#pragma unroll
        for (int mi = 0; mi < 4; ++mi)
#pragma unroll
            for (int ni = 0; ni < 4; ++ni)
                acc[mi][ni] = __builtin_amdgcn_mfma_f32_16x16x32_bf16(av[mi], bv[ni], acc[mi][ni], 0, 0, 0);
    }
#pragma unroll
    for (int mi = 0; mi < 4; ++mi)
#pragma unroll
        for (int r = 0; r < 4; ++r) {
            int mrow = m0 + wy * 64 + mi * 16 + lq * 4 + r;
#pragma unroll
            for (int ni = 0; ni < 4; ++ni)
                H[(size_t)mrow * 3072 + n0 + wx * 64 + ni * 16 + l15] = acc[mi][ni][r];
        }
}

// ---------------- small projections
__global__ void small_proj(const float* __restrict__ speaker_emb,
                           const float* __restrict__ bucket_emb,
                           const float* __restrict__ sp_W0,
                           float* __restrict__ spk_proj, float* __restrict__ bkt_proj)
{
    int r = blockIdx.x; // 0..11
    const float* e; const float* W; float* out;
    if (r < 2) { e = speaker_emb + r * 20; W = sp_W0 + (size_t)1536 * 1024; out = spk_proj + r * 1024; }
    else       { e = bucket_emb + (r - 2) * 20; W = sp_W0 + (size_t)1556 * 1024; out = bkt_proj + (r - 2) * 1024; }
    float ek[20];
#pragma unroll
    for (int k = 0; k < 20; ++k) ek[k] = e[k];
    for (int f = threadIdx.x; f < 1024; f += blockDim.x) {
        float s = 0.f;
#pragma unroll
        for (int k = 0; k < 20; ++k) s = fmaf(ek[k], W[(size_t)k * 1024 + f], s);
        out[f] = s;
    }
}

// ---------------- mention scores
__global__ __launch_bounds__(256) void mention_score(
    const float* __restrict__ H, const float* __restrict__ ms_b0,
    const float* __restrict__ ms_W1, const float* __restrict__ ms_b1,
    float* __restrict__ ms)
{
    int m = blockIdx.x;
    float v = 0.f;
    for (int f = threadIdx.x; f < 1024; f += 256) {
        float h = H[(size_t)m * 3072 + f] + ms_b0[f];
        v += fmaxf(h, 0.f) * ms_W1[f];
    }
#pragma unroll
    for (int o = 1; o < 64; o <<= 1) v += __shfl_xor(v, o);
    __shared__ float sm[4];
    if ((threadIdx.x & 63) == 0) sm[threadIdx.x >> 6] = v;
    __syncthreads();
    if (threadIdx.x == 0) ms[m] = sm[0] + sm[1] + sm[2] + sm[3] + ms_b1[0];
}

// ---------------- pair scorer v7: grid (1024 m, 2 fh), 1024 threads / 16 waves.
// Block = ALL 128 c x one f-half (512 f): halves B (Wfrag) L2 traffic vs the c-half
// split (both c-half blocks read identical B), and wc-paired waves share a B stream
// (L1 catch). A-tile 128 x 512 in LDS (138 KB) -> 1 block/CU, 16 waves (4/SIMD; reg
// cap anyway at acc=64 AGPR + ~50 VGPR). Wave (wc = wave>>3, wf = wave&7) computes
// 64c x 64f with the r5-proven acc[2][2] body. LDSR=520: 16B rows -> ds_read_b128
// (2 DS ops/k-step, was 4) at uniform 8-accesses/bank. A-build: 8 threads per row,
// uint4 stores (uniform bank distribution), per-lane-sequential 128B line reads.
__global__ __launch_bounds__(1024, 4) void pair_mfma(
    const ushort* __restrict__ embb, const ushort* __restrict__ Wfrag,
    const float* __restrict__ H, const float* __restrict__ spk_proj,
    const float* __restrict__ bkt_proj, const float* __restrict__ sp_b0,
    const float* __restrict__ sp_W1, const int* __restrict__ speaker,
    float* __restrict__ slow0, float* __restrict__ slow1)
{
    extern __shared__ ushort Alds[];                  // 128*LDSR ushorts
    float* red = (float*)(Alds + 128 * LDSR);         // 16*64 floats
    int* meta_ss = (int*)(red + 16 * 64);             // 128 ints
    int* meta_bk = meta_ss + 128;                     // 128 ints
    const int m = blockIdx.x;
    const int fh = blockIdx.y;                        // 0 or 1 (f-half)
    const int tid = threadIdx.x;
    const int spk_m = speaker[m];

    // ---- build A[c][k] = bf16(em[k]*ea[k]) in LDS + per-c metadata (128 rows)
    {
        const int c = tid >> 3;                       // 0..127
        const int kh = (tid & 7) * 64;
        int a = m - 1 - c; if (a < 0) a = 0;
        const ushort* ea = embb + (size_t)a * 512 + kh;
        const ushort* em = embb + (size_t)m * 512 + kh;
        ushort* dst = Alds + c * LDSR + kh;
#pragma unroll
        for (int j = 0; j < 64; j += 8) {
            bf16x8 va = *(const bf16x8*)(ea + j);
            bf16x8 vm = *(const bf16x8*)(em + j);
            uint pr[4];
#pragma unroll
            for (int p = 0; p < 4; ++p) {
                float q0 = bf16_to_f((ushort)va[2 * p])     * bf16_to_f((ushort)vm[2 * p]);
                float q1 = bf16_to_f((ushort)va[2 * p + 1]) * bf16_to_f((ushort)vm[2 * p + 1]);
                pr[p] = __builtin_amdgcn_perm(__float_as_uint(q1), __float_as_uint(q0), 0x07060302u);
            }
            *(uint4*)__builtin_assume_aligned(dst + j, 16) = *(uint4*)&pr[0];  // one 16B store
        }
        if ((tid & 7) == 0) {
            meta_ss[c] = (speaker[a] == spk_m) ? 1 : 0;
            int off = c + 1;                          // 1..128
            int bk;
            if (off <= 4) bk = off;
            else { bk = 31 - __clz(off) + 3; if (bk > 9) bk = 9; }
            meta_bk[c] = bk;
        }
    }
    __syncthreads();

    const int lane = tid & 63;
    const int wave = __builtin_amdgcn_readfirstlane(tid >> 6);   // 0..15, wave-uniform
    const int wc = wave >> 3, wf = wave & 7;
    const int l31 = lane & 31, k5 = lane >> 5;

    const int f0 = fh * 512 + wf * 64;
    // B: fragment-major; per k-step s the wave reads contiguous 1 KB per tile.
    // wc-paired waves (same wf) read the SAME stream -> L1 reuse.
    const ushort* bb = Wfrag + (size_t)(fh * 16 + wf * 2) * 16384 + (size_t)lane * 8;
    const ushort* ab = Alds + (wc * 64 + l31) * LDSR + k5 * 8;

    f32x16 acc[2][2];
#pragma unroll
    for (int i = 0; i < 2; ++i)
#pragma unroll
        for (int j = 0; j < 2; ++j) acc[i][j] = (f32x16)0.f;

#pragma unroll 2
    for (int s = 0; s < 32; ++s) {
        bf16x8 b0 = *(const bf16x8*)(bb + s * 512);
        bf16x8 b1 = *(const bf16x8*)(bb + 16384 + s * 512);
        bf16x8 a0 = ld_lds16(ab + s * 16);
        bf16x8 a1 = ld_lds16(ab + 32 * LDSR + s * 16);
        __builtin_amdgcn_s_setprio(1);
        acc[0][0] = __builtin_amdgcn_mfma_f32_32x32x16_bf16(a0, b0, acc[0][0], 0, 0, 0);
        acc[0][1] = __builtin_amdgcn_mfma_f32_32x32x16_bf16(a0, b1, acc[0][1], 0, 0, 0);
        acc[1][0] = __builtin_amdgcn_mfma_f32_32x32x16_bf16(a1, b0, acc[1][0], 0, 0, 0);
        acc[1][1] = __builtin_amdgcn_mfma_f32_32x32x16_bf16(a1, b1, acc[1][1], 0, 0, 0);
        __builtin_amdgcn_s_setprio(0);
    }

    // ---- epilogue (constants loaded here, not live during k-loop)
    float srcb[2], w1v[2], sp0v[2], sp1v[2];
#pragma unroll
    for (int ni = 0; ni < 2; ++ni) {
        int fcol = f0 + ni * 32 + l31;
        srcb[ni] = H[(size_t)m * 3072 + 1024 + fcol] + sp_b0[fcol];
        w1v[ni]  = sp_W1[fcol];
        sp0v[ni] = spk_proj[fcol];
        sp1v[ni] = spk_proj[1024 + fcol];
    }
    // C/D 32x32 layout: col=lane&31, row=(reg&3)+8*(reg>>2)+4*(lane>>5)
#pragma unroll
    for (int mi = 0; mi < 2; ++mi) {
#pragma unroll
        for (int reg = 0; reg < 16; ++reg) {
            const int cl = mi * 32 + 4 * k5 + (reg & 3) + 8 * (reg >> 2);  // 0..63 within wc
            const int c = wc * 64 + cl;
            int a = m - 1 - c; if (a < 0) a = 0;
            const int ss = meta_ss[c];
            const int bk = meta_bk[c];
            const float* antp = H + (size_t)a * 3072 + 2048;
            float s = 0.f;
#pragma unroll
            for (int ni = 0; ni < 2; ++ni) {
                const int fcol = f0 + ni * 32 + l31;
                float bval = bkt_proj[(size_t)bk * 1024 + fcol];   // 40 KB table, L1/L2-hot
                float pre = acc[mi][ni][reg] + srcb[ni] + antp[fcol] + (ss ? sp1v[ni] : sp0v[ni]) + bval;
                s += fmaxf(pre, 0.f) * w1v[ni];
            }
            s += __shfl_xor(s, 1); s += __shfl_xor(s, 2); s += __shfl_xor(s, 4);
            s += __shfl_xor(s, 8); s += __shfl_xor(s, 16);
            if (l31 == 0) red[wave * 64 + cl] = s;
        }
    }
    __syncthreads();
    if (tid < 128) {
        const int c = tid;
        const int wcc = c >> 6, cl = c & 63;
        float s = 0.f;
#pragma unroll
        for (int i = 0; i < 8; ++i) s += red[(wcc * 8 + i) * 64 + cl];
        float* sout = fh ? slow1 : slow0;             // disjoint: plain store, no atomic
        sout[(size_t)m * 128 + c] = s;
    }
}

// ---------------- softmax + per-mention loss
__device__ __forceinline__ float bsum2(float v, float* sm) {
#pragma unroll
    for (int o = 1; o < 64; o <<= 1) v += __shfl_xor(v, o);
    __syncthreads();
    if ((threadIdx.x & 63) == 0) sm[threadIdx.x >> 6] = v;
    __syncthreads();
    return sm[0] + sm[1];
}
__device__ __forceinline__ float bmax2(float v, float* sm) {
#pragma unroll
    for (int o = 1; o < 64; o <<= 1) v = fmaxf(v, __shfl_xor(v, o));
    __syncthreads();
    if ((threadIdx.x & 63) == 0) sm[threadIdx.x >> 6] = v;
    __syncthreads();
    return fmaxf(sm[0], sm[1]);
}

__global__ __launch_bounds__(128) void softmax_loss(
    const float* __restrict__ slow0, const float* __restrict__ slow1,
    const float* __restrict__ ms,
    const float* __restrict__ sp_b1, const int* __restrict__ cluster,
    float* __restrict__ out, float* __restrict__ loss_partial)
{
    const int m = blockIdx.x, c = threadIdx.x;
    __shared__ float sm[2];
    const int raw = m - 1 - c;
    const bool maskv = raw >= 0;
    const int a = maskv ? raw : 0;
    float score = slow0[(size_t)m * 128 + c] + slow1[(size_t)m * 128 + c]
                + sp_b1[0] + ms[m] + ms[a];
    if (!maskv) score = -INFINITY;

    float mx = fmaxf(bmax2(score, sm), 0.f);
    float e = expf(score - mx);
    float e0 = expf(0.f - mx);
    float sum = bsum2(e, sm) + e0;
    float p = e / sum, p0 = e0 / sum;
    const float eps = 1e-6f;
    p  = fminf(fmaxf(p,  eps), 1.f - eps);
    p0 = fminf(fmaxf(p0, eps), 1.f - eps);
    float sum2 = bsum2(p, sm) + p0;
    p /= sum2; p0 /= sum2;
    out[(size_t)m * 129 + 1 + c] = p;
    if (c == 0) out[(size_t)m * 129] = p0;

    const int cid = cluster[m];
    const bool lbl = maskv && (cid > 0) && (cluster[a] == cid);
    float anyc = bsum2(lbl ? 1.f : 0.f, sm);
    float lsum = bsum2(lbl ? -logf(p) : 0.f, sm);
    if (c == 0) {
        if (anyc == 0.f) lsum += -logf(p0);
        loss_partial[m] = lsum;
    }
}

__global__ void loss_sum(const float* __restrict__ lp, float* __restrict__ out) {
    float v = 0.f;
    for (int i = threadIdx.x; i < 1024; i += 256) v += lp[i];
#pragma unroll
    for (int o = 1; o < 64; o <<= 1) v += __shfl_xor(v, o);
    __shared__ float sm[4];
    if ((threadIdx.x & 63) == 0) sm[threadIdx.x >> 6] = v;
    __syncthreads();
    if (threadIdx.x == 0) out[(size_t)1024 * 129] = sm[0] + sm[1] + sm[2] + sm[3];
}

extern "C" void kernel_launch(void* const* d_in, const int* in_sizes, int n_in,
                              void* d_out, int out_size, void* d_ws, size_t ws_size,
                              hipStream_t stream)
{
    const float* emb   = (const float*)d_in[0];
    const int*   clus  = (const int*)  d_in[1];
    const int*   spk   = (const int*)  d_in[2];
    const float* ms_W0 = (const float*)d_in[3];
    const float* ms_b0 = (const float*)d_in[4];
    const float* ms_W1 = (const float*)d_in[5];
    const float* ms_b1 = (const float*)d_in[6];
    const float* sp_W0 = (const float*)d_in[7];
    const float* sp_b0 = (const float*)d_in[8];
    const float* sp_W1 = (const float*)d_in[9];
    const float* sp_b1 = (const float*)d_in[10];
    const float* spke  = (const float*)d_in[11];
    const float* bkte  = (const float*)d_in[12];

    float* ws = (float*)d_ws;
    float* H        = ws;
    float* slow0    = ws + 3145728;
    float* spk_proj = ws + 3276800;
    float* bkt_proj = ws + 3278848;
    float* msc      = ws + 3289088;
    float* lossp    = ws + 3290112;
    ushort* embb    = (ushort*)(ws + 3291136);
    ushort* Wall    = (ushort*)(ws + 3553280);
    ushort* Wfrag   = Wall + (size_t)3072 * 512;   // reuse W_prod region, frag-major
    float* slow1    = ws + 4601856;                // after Wall region
    float* out = (float*)d_out;

    const int pair_lds = 128 * LDSR * 2 + 16 * 64 * 4 + 2 * 128 * 4;   // 138240 B

    static bool attr_set = false;
    if (!attr_set) {
        hipFuncSetAttribute((const void*)&pair_mfma,
                            hipFuncAttributeMaxDynamicSharedMemorySize,
                            pair_lds);
        attr_set = true;
    }

    hipLaunchKernelGGL(prep_emb, dim3(1024), dim3(256), 0, stream, emb, embb);
    hipLaunchKernelGGL(prep_wall, dim3(8, 48), dim3(256), 0, stream, ms_W0, sp_W0, Wall);
    hipLaunchKernelGGL(prep_wfrag, dim3(1024), dim3(64), 0, stream,
                       sp_W0 + (size_t)1024 * 1024, Wfrag);     // W_prod
    hipLaunchKernelGGL(gemm_h_mfma, dim3(24, 8), dim3(256), 0, stream, embb, Wall, H);
    hipLaunchKernelGGL(small_proj, dim3(12), dim3(256), 0, stream, spke, bkte, sp_W0, spk_proj, bkt_proj);
    hipLaunchKernelGGL(mention_score, dim3(1024), dim3(256), 0, stream, H, ms_b0, ms_W1, ms_b1, msc);
    hipLaunchKernelGGL(pair_mfma, dim3(1024, 2), dim3(1024), pair_lds, stream,
                       embb, Wfrag, H, spk_proj, bkt_proj, sp_b0, sp_W1, spk, slow0, slow1);
    hipLaunchKernelGGL(softmax_loss, dim3(1024), dim3(128), 0, stream,
                       slow0, slow1, msc, sp_b1, clus, out, lossp);
    hipLaunchKernelGGL(loss_sum, dim3(1), dim3(256), 0, stream, lossp, out);
}

// Round 7
// 360.760 us; speedup vs baseline: 1.1171x; 1.1171x over previous
//
#include <hip/hip_runtime.h>
#include <math.h>

// Problem constants (B=1)
#define MM 1024
#define DD 512
#define CC 128
#define LDSR 516   // A row stride in ushorts: 1032 B = 258 dw ≡ 2 (mod 32).
                   // b64 reads: each bank gets 4 accesses/wave = 2/phase -> free (m136).

// ws layout (floats):
//  H[1024][3072]      @ 0        (0..1023 ms-hidden, 1024.. src_proj, 2048.. ant_proj)
//  slow0[1024][128]   @ 3145728  (fh=0 partials)
//  spk_proj[2][1024]  @ 3276800
//  bkt_proj[10][1024] @ 3278848
//  ms[1024]           @ 3289088
//  lossp[1024]        @ 3290112
//  embb bf16[1024][512]  @ 3291136
//  Wall bf16[4096][512]  @ 3553280
//    rows [0,1024)=ms_W0^T, [1024,2048)=W_src^T, [2048,3072)=W_ant^T
//    region [3072,4096) reused as Wfrag16 (fragment-major W_prod, 16x16 format):
//      [t16:64][s:16][lane:64][8] bf16; element (f = t16*16 + (lane&15),
//      k = s*32 + ((lane>>4)&3)*8 + j) at ((t16*16+s)*64+lane)*8+j
//  slow1[1024][128]   @ 4601856  (fh=1 partials)

typedef __attribute__((ext_vector_type(8))) short bf16x8;
typedef __attribute__((ext_vector_type(4), aligned(8))) short bf16x4a;
typedef __attribute__((ext_vector_type(4))) float f32x4;

__device__ __forceinline__ ushort bf16_rn(float x) {
    uint u = __float_as_uint(x);
    uint r = u + 0x7fffu + ((u >> 16) & 1u);
    return (ushort)(r >> 16);
}
__device__ __forceinline__ float bf16_to_f(ushort u) {
    return __uint_as_float(((uint)u) << 16);
}
__device__ __forceinline__ bf16x8 ld_lds16(const ushort* p) {   // two ds_read_b64 (8B-aligned)
    bf16x4a lo = *(const bf16x4a*)p;
    bf16x4a hi = *(const bf16x4a*)(p + 4);
    return __builtin_shufflevector(lo, hi, 0, 1, 2, 3, 4, 5, 6, 7);
}

// ---------------- prep: emb fp32 -> bf16
__global__ __launch_bounds__(256) void prep_emb(const float* __restrict__ emb,
                                                ushort* __restrict__ embb)
{
    int i = blockIdx.x * 256 + threadIdx.x;
    float2 v = ((const float2*)emb)[i];
    ushort2 o;
    o.x = bf16_rn(v.x);
    o.y = bf16_rn(v.y);
    ((ushort2*)embb)[i] = o;
}

// ---------------- prep: transpose+convert W0 blocks 0..2 -> Wall[3072 n][512 k] bf16
__global__ __launch_bounds__(256) void prep_wall(const float* __restrict__ ms_W0,
                                                 const float* __restrict__ sp_W0,
                                                 ushort* __restrict__ Wall)
{
    __shared__ float t[64][65];
    const int k0 = blockIdx.x * 64;   // 8
    const int n0 = blockIdx.y * 64;   // 48
    const int g = n0 >> 10;
    const float* src = (g == 0) ? ms_W0 : (sp_W0 + (size_t)(g - 1) * 512 * 1024);
    const int col0 = n0 & 1023;
    const int tr = threadIdx.x >> 6, tc = threadIdx.x & 63;
#pragma unroll
    for (int i = 0; i < 16; ++i) {
        int k = tr + i * 4;
        t[k][tc] = src[(size_t)(k0 + k) * 1024 + col0 + tc];
    }
    __syncthreads();
    const int f = threadIdx.x >> 2;
    const int c4 = threadIdx.x & 3;
    ushort tmp[16];
#pragma unroll
    for (int j = 0; j < 16; ++j) tmp[j] = bf16_rn(t[c4 * 16 + j][f]);
    uint4* dst = (uint4*)(Wall + (size_t)(n0 + f) * 512 + k0 + c4 * 16);
    dst[0] = *(uint4*)&tmp[0];
    dst[1] = *(uint4*)&tmp[8];
}

// ---------------- prep: W_prod [k=512][f=1024] -> 16x16 fragment-major
__global__ __launch_bounds__(64) void prep_wfrag16(const float* __restrict__ W,
                                                   ushort* __restrict__ dst_frag)
{
    const int ts = blockIdx.x;            // t16*16 + s, 0..1023
    const int l = threadIdx.x;            // 0..63
    const int t16 = ts >> 4, s = ts & 15;
    const int f = t16 * 16 + (l & 15);
    const int kb = s * 32 + ((l >> 4) & 3) * 8;
    ushort tmp[8];
#pragma unroll
    for (int j = 0; j < 8; ++j) tmp[j] = bf16_rn(W[(size_t)(kb + j) * 1024 + f]);
    uint4* dst = (uint4*)(dst_frag + ((size_t)ts * 64 + l) * 8);
    *dst = *(uint4*)&tmp[0];
}

// ---------------- H = emb @ [ms_W0 | W_src | W_ant] via MFMA (1024x512x3072)
__global__ __launch_bounds__(256) void gemm_h_mfma(
    const ushort* __restrict__ embb, const ushort* __restrict__ Wall,
    float* __restrict__ H)
{
    const int n0 = blockIdx.x * 128;  // 24
    const int m0 = blockIdx.y * 128;  // 8
    const int lane = threadIdx.x & 63, wave = threadIdx.x >> 6;
    const int wx = wave & 1, wy = wave >> 1;
    const int l15 = lane & 15, lq = lane >> 4;

    const ushort* arow[4];
#pragma unroll
    for (int mi = 0; mi < 4; ++mi)
        arow[mi] = embb + (size_t)(m0 + wy * 64 + mi * 16 + l15) * 512;
    const ushort* brow[4];
#pragma unroll
    for (int ni = 0; ni < 4; ++ni)
        brow[ni] = Wall + (size_t)(n0 + wx * 64 + ni * 16 + l15) * 512;

    f32x4 acc[4][4];
#pragma unroll
    for (int i = 0; i < 4; ++i)
#pragma unroll
        for (int j = 0; j < 4; ++j) acc[i][j] = (f32x4)0.f;

    for (int kt = 0; kt < 512; kt += 32) {
        const int ko = kt + lq * 8;
        bf16x8 av[4], bv[4];
#pragma unroll
        for (int mi = 0; mi < 4; ++mi) av[mi] = *(const bf16x8*)(arow[mi] + ko);
#pragma unroll
        for (int ni = 0; ni < 4; ++ni) bv[ni] = *(const bf16x8*)(brow[ni] + ko);
#pragma unroll
        for (int mi = 0; mi < 4; ++mi)
#pragma unroll
            for (int ni = 0; ni < 4; ++ni)
                acc[mi][ni] = __builtin_amdgcn_mfma_f32_16x16x32_bf16(av[mi], bv[ni], acc[mi][ni], 0, 0, 0);
    }
#pragma unroll
    for (int mi = 0; mi < 4; ++mi)
#pragma unroll
        for (int r = 0; r < 4; ++r) {
            int mrow = m0 + wy * 64 + mi * 16 + lq * 4 + r;
#pragma unroll
            for (int ni = 0; ni < 4; ++ni)
                H[(size_t)mrow * 3072 + n0 + wx * 64 + ni * 16 + l15] = acc[mi][ni][r];
        }
}

// ---------------- small projections
__global__ void small_proj(const float* __restrict__ speaker_emb,
                           const float* __restrict__ bucket_emb,
                           const float* __restrict__ sp_W0,
                           float* __restrict__ spk_proj, float* __restrict__ bkt_proj)
{
    int r = blockIdx.x; // 0..11
    const float* e; const float* W; float* out;
    if (r < 2) { e = speaker_emb + r * 20; W = sp_W0 + (size_t)1536 * 1024; out = spk_proj + r * 1024; }
    else       { e = bucket_emb + (r - 2) * 20; W = sp_W0 + (size_t)1556 * 1024; out = bkt_proj + (r - 2) * 1024; }
    float ek[20];
#pragma unroll
    for (int k = 0; k < 20; ++k) ek[k] = e[k];
    for (int f = threadIdx.x; f < 1024; f += blockDim.x) {
        float s = 0.f;
#pragma unroll
        for (int k = 0; k < 20; ++k) s = fmaf(ek[k], W[(size_t)k * 1024 + f], s);
        out[f] = s;
    }
}

// ---------------- mention scores
__global__ __launch_bounds__(256) void mention_score(
    const float* __restrict__ H, const float* __restrict__ ms_b0,
    const float* __restrict__ ms_W1, const float* __restrict__ ms_b1,
    float* __restrict__ ms)
{
    int m = blockIdx.x;
    float v = 0.f;
    for (int f = threadIdx.x; f < 1024; f += 256) {
        float h = H[(size_t)m * 3072 + f] + ms_b0[f];
        v += fmaxf(h, 0.f) * ms_W1[f];
    }
#pragma unroll
    for (int o = 1; o < 64; o <<= 1) v += __shfl_xor(v, o);
    __shared__ float sm[4];
    if ((threadIdx.x & 63) == 0) sm[threadIdx.x >> 6] = v;
    __syncthreads();
    if (threadIdx.x == 0) ms[m] = sm[0] + sm[1] + sm[2] + sm[3] + ms_b1[0];
}

// ---------------- pair scorer v8: 16x16 MFMA, 8 waves/SIMD occupancy play.
// Grid (1024 m, 8 = fh*4 + cq); block 512 thr / 8 waves; A-tile 32c x 512k in LDS
// (33.5 KB) -> 4 blocks/CU; acc = f32x4[2][2] = 16 AGPR; launch_bounds(512,8)
// forces <=64 unified regs -> 8 waves/SIMD = 32 waves/CU (HW max). The ~45%
// neither-pipe-busy stall (measured r0..r6, invariant across traffic fixes) is
// the target: 2x TLP to hide L2/epilogue latency.
// Wave w covers 32c x 64f via ft2-loop of two 32x32 tiles (acc reused).
__global__ __launch_bounds__(512, 8) void pair_mfma(
    const ushort* __restrict__ embb, const ushort* __restrict__ Wfrag16,
    const float* __restrict__ H, const float* __restrict__ spk_proj,
    const float* __restrict__ bkt_proj, const float* __restrict__ sp_b0,
    const float* __restrict__ sp_W1, const int* __restrict__ speaker,
    float* __restrict__ slow0, float* __restrict__ slow1)
{
    extern __shared__ ushort Alds[];                  // 32*LDSR ushorts
    float* red = (float*)(Alds + 32 * LDSR);          // 8*32 floats
    int* meta_ss = (int*)(red + 8 * 32);              // 32 ints
    int* meta_bk = meta_ss + 32;                      // 32 ints
    const int m = blockIdx.x;
    const int cq = blockIdx.y & 3;                    // c-quarter
    const int fh = blockIdx.y >> 2;                   // f-half
    const int cbase = cq * 32;
    const int tid = threadIdx.x;
    const int spk_m = speaker[m];

    // ---- build A[c][k] = bf16(em[k]*ea[k]) in LDS + per-c metadata (32 rows)
    // lane->row mapping (c = tid&31): 8B stores land 4 accesses/bank/wave = free.
    {
        const int c = tid & 31;
        const int kh = (tid >> 5) * 32;               // 16 chunks of 32 ushorts
        int a = m - 1 - (cbase + c); if (a < 0) a = 0;
        const ushort* ea = embb + (size_t)a * 512 + kh;
        const ushort* em = embb + (size_t)m * 512 + kh;
        ushort* dst = Alds + c * LDSR + kh;
#pragma unroll
        for (int j = 0; j < 32; j += 8) {
            bf16x8 va = *(const bf16x8*)(ea + j);
            bf16x8 vm = *(const bf16x8*)(em + j);
            uint pr[4];
#pragma unroll
            for (int p = 0; p < 4; ++p) {
                float q0 = bf16_to_f((ushort)va[2 * p])     * bf16_to_f((ushort)vm[2 * p]);
                float q1 = bf16_to_f((ushort)va[2 * p + 1]) * bf16_to_f((ushort)vm[2 * p + 1]);
                pr[p] = __builtin_amdgcn_perm(__float_as_uint(q1), __float_as_uint(q0), 0x07060302u);
            }
            *(uint2*)(dst + j)     = *(uint2*)&pr[0];   // 8B stores (rows are 8B-aligned)
            *(uint2*)(dst + j + 4) = *(uint2*)&pr[2];
        }
        if (tid < 32) {                               // c == tid
            meta_ss[c] = (speaker[a] == spk_m) ? 1 : 0;
            int off = cbase + c + 1;                  // 1..128
            int bk;
            if (off <= 4) bk = off;
            else { bk = 31 - __clz(off) + 3; if (bk > 9) bk = 9; }
            meta_bk[c] = bk;
        }
    }
    __syncthreads();

    const int lane = tid & 63;
    const int wave = __builtin_amdgcn_readfirstlane(tid >> 6);   // 0..7, wave-uniform
    const int l15 = lane & 15, lq = lane >> 4;
    const ushort* ab0 = Alds + l15 * LDSR + lq * 8;   // ct=0; ct=1 at +16*LDSR

#pragma unroll 1
    for (int ft2 = 0; ft2 < 2; ++ft2) {
        const int f0a = fh * 512 + wave * 64 + ft2 * 32;
        // B stream: t16 = f0a/16; per step s, 1 KB contiguous per f-tile, stride 512.
        const ushort* bb0 = Wfrag16 + (size_t)(fh * 32 + wave * 4 + ft2 * 2) * 8192
                                    + (size_t)lane * 8;
        f32x4 acc[2][2];
#pragma unroll
        for (int i = 0; i < 2; ++i)
#pragma unroll
            for (int j = 0; j < 2; ++j) acc[i][j] = (f32x4)0.f;

#pragma unroll 2
        for (int s = 0; s < 16; ++s) {
            bf16x8 b0 = *(const bf16x8*)(bb0 + s * 512);
            bf16x8 b1 = *(const bf16x8*)(bb0 + 8192 + s * 512);
            bf16x8 a0 = ld_lds16(ab0 + s * 32);
            bf16x8 a1 = ld_lds16(ab0 + 16 * LDSR + s * 32);
            __builtin_amdgcn_s_setprio(1);
            acc[0][0] = __builtin_amdgcn_mfma_f32_16x16x32_bf16(a0, b0, acc[0][0], 0, 0, 0);
            acc[0][1] = __builtin_amdgcn_mfma_f32_16x16x32_bf16(a0, b1, acc[0][1], 0, 0, 0);
            acc[1][0] = __builtin_amdgcn_mfma_f32_16x16x32_bf16(a1, b0, acc[1][0], 0, 0, 0);
            acc[1][1] = __builtin_amdgcn_mfma_f32_16x16x32_bf16(a1, b1, acc[1][1], 0, 0, 0);
            __builtin_amdgcn_s_setprio(0);
        }

        // ---- epilogue for this 32f slice
        float srcb[2], w1v[2], sp0v[2], sp1v[2];
#pragma unroll
        for (int fi = 0; fi < 2; ++fi) {
            int fcol = f0a + fi * 16 + l15;
            srcb[fi] = H[(size_t)m * 3072 + 1024 + fcol] + sp_b0[fcol];
            w1v[fi]  = sp_W1[fcol];
            sp0v[fi] = spk_proj[fcol];
            sp1v[fi] = spk_proj[1024 + fcol];
        }
        // C/D 16x16 layout: col(f) = lane&15, row(c) = lq*4 + reg
#pragma unroll
        for (int ct = 0; ct < 2; ++ct) {
#pragma unroll
            for (int reg = 0; reg < 4; ++reg) {
                const int cl = ct * 16 + lq * 4 + reg;        // 0..31 local
                int a = m - 1 - (cbase + cl); if (a < 0) a = 0;
                const int ss = meta_ss[cl];
                const int bk = meta_bk[cl];
                const float* antp = H + (size_t)a * 3072 + 2048;
                float s = 0.f;
#pragma unroll
                for (int fi = 0; fi < 2; ++fi) {
                    const int fcol = f0a + fi * 16 + l15;
                    float bval = bkt_proj[(size_t)bk * 1024 + fcol];
                    float pre = acc[ct][fi][reg] + srcb[fi] + antp[fcol]
                              + (ss ? sp1v[fi] : sp0v[fi]) + bval;
                    s += fmaxf(pre, 0.f) * w1v[fi];
                }
                // reduce over l15 (lane bits 0..3)
                s += __shfl_xor(s, 1); s += __shfl_xor(s, 2);
                s += __shfl_xor(s, 4); s += __shfl_xor(s, 8);
                if (l15 == 0) {
                    if (ft2 == 0) red[wave * 32 + cl] = s;
                    else          red[wave * 32 + cl] += s;   // same wave: no race
                }
            }
        }
    }
    __syncthreads();
    if (tid < 32) {
        float s = 0.f;
#pragma unroll
        for (int i = 0; i < 8; ++i) s += red[i * 32 + tid];
        float* sout = fh ? slow1 : slow0;             // disjoint c-range per cq: plain store
        sout[(size_t)m * 128 + cbase + tid] = s;
    }
}

// ---------------- softmax + per-mention loss
__device__ __forceinline__ float bsum2(float v, float* sm) {
#pragma unroll
    for (int o = 1; o < 64; o <<= 1) v += __shfl_xor(v, o);
    __syncthreads();
    if ((threadIdx.x & 63) == 0) sm[threadIdx.x >> 6] = v;
    __syncthreads();
    return sm[0] + sm[1];
}
__device__ __forceinline__ float bmax2(float v, float* sm) {
#pragma unroll
    for (int o = 1; o < 64; o <<= 1) v = fmaxf(v, __shfl_xor(v, o));
    __syncthreads();
    if ((threadIdx.x & 63) == 0) sm[threadIdx.x >> 6] = v;
    __syncthreads();
    return fmaxf(sm[0], sm[1]);
}

__global__ __launch_bounds__(128) void softmax_loss(
    const float* __restrict__ slow0, const float* __restrict__ slow1,
    const float* __restrict__ ms,
    const float* __restrict__ sp_b1, const int* __restrict__ cluster,
    float* __restrict__ out, float* __restrict__ loss_partial)
{
    const int m = blockIdx.x, c = threadIdx.x;
    __shared__ float sm[2];
    const int raw = m - 1 - c;
    const bool maskv = raw >= 0;
    const int a = maskv ? raw : 0;
    float score = slow0[(size_t)m * 128 + c] + slow1[(size_t)m * 128 + c]
                + sp_b1[0] + ms[m] + ms[a];
    if (!maskv) score = -INFINITY;

    float mx = fmaxf(bmax2(score, sm), 0.f);
    float e = expf(score - mx);
    float e0 = expf(0.f - mx);
    float sum = bsum2(e, sm) + e0;
    float p = e / sum, p0 = e0 / sum;
    const float eps = 1e-6f;
    p  = fminf(fmaxf(p,  eps), 1.f - eps);
    p0 = fminf(fmaxf(p0, eps), 1.f - eps);
    float sum2 = bsum2(p, sm) + p0;
    p /= sum2; p0 /= sum2;
    out[(size_t)m * 129 + 1 + c] = p;
    if (c == 0) out[(size_t)m * 129] = p0;

    const int cid = cluster[m];
    const bool lbl = maskv && (cid > 0) && (cluster[a] == cid);
    float anyc = bsum2(lbl ? 1.f : 0.f, sm);
    float lsum = bsum2(lbl ? -logf(p) : 0.f, sm);
    if (c == 0) {
        if (anyc == 0.f) lsum += -logf(p0);
        loss_partial[m] = lsum;
    }
}

__global__ void loss_sum(const float* __restrict__ lp, float* __restrict__ out) {
    float v = 0.f;
    for (int i = threadIdx.x; i < 1024; i += 256) v += lp[i];
#pragma unroll
    for (int o = 1; o < 64; o <<= 1) v += __shfl_xor(v, o);
    __shared__ float sm[4];
    if ((threadIdx.x & 63) == 0) sm[threadIdx.x >> 6] = v;
    __syncthreads();
    if (threadIdx.x == 0) out[(size_t)1024 * 129] = sm[0] + sm[1] + sm[2] + sm[3];
}

extern "C" void kernel_launch(void* const* d_in, const int* in_sizes, int n_in,
                              void* d_out, int out_size, void* d_ws, size_t ws_size,
                              hipStream_t stream)
{
    const float* emb   = (const float*)d_in[0];
    const int*   clus  = (const int*)  d_in[1];
    const int*   spk   = (const int*)  d_in[2];
    const float* ms_W0 = (const float*)d_in[3];
    const float* ms_b0 = (const float*)d_in[4];
    const float* ms_W1 = (const float*)d_in[5];
    const float* ms_b1 = (const float*)d_in[6];
    const float* sp_W0 = (const float*)d_in[7];
    const float* sp_b0 = (const float*)d_in[8];
    const float* sp_W1 = (const float*)d_in[9];
    const float* sp_b1 = (const float*)d_in[10];
    const float* spke  = (const float*)d_in[11];
    const float* bkte  = (const float*)d_in[12];

    float* ws = (float*)d_ws;
    float* H        = ws;
    float* slow0    = ws + 3145728;
    float* spk_proj = ws + 3276800;
    float* bkt_proj = ws + 3278848;
    float* msc      = ws + 3289088;
    float* lossp    = ws + 3290112;
    ushort* embb    = (ushort*)(ws + 3291136);
    ushort* Wall    = (ushort*)(ws + 3553280);
    ushort* Wfrag16 = Wall + (size_t)3072 * 512;   // reuse W_prod region, frag-major 16x16
    float* slow1    = ws + 4601856;                // after Wall region
    float* out = (float*)d_out;

    const int pair_lds = 32 * LDSR * 2 + 8 * 32 * 4 + 2 * 32 * 4;   // 34304 B

    static bool attr_set = false;
    if (!attr_set) {
        hipFuncSetAttribute((const void*)&pair_mfma,
                            hipFuncAttributeMaxDynamicSharedMemorySize,
                            pair_lds);
        attr_set = true;
    }

    hipLaunchKernelGGL(prep_emb, dim3(1024), dim3(256), 0, stream, emb, embb);
    hipLaunchKernelGGL(prep_wall, dim3(8, 48), dim3(256), 0, stream, ms_W0, sp_W0, Wall);
    hipLaunchKernelGGL(prep_wfrag16, dim3(1024), dim3(64), 0, stream,
                       sp_W0 + (size_t)1024 * 1024, Wfrag16);   // W_prod
    hipLaunchKernelGGL(gemm_h_mfma, dim3(24, 8), dim3(256), 0, stream, embb, Wall, H);
    hipLaunchKernelGGL(small_proj, dim3(12), dim3(256), 0, stream, spke, bkte, sp_W0, spk_proj, bkt_proj);
    hipLaunchKernelGGL(mention_score, dim3(1024), dim3(256), 0, stream, H, ms_b0, ms_W1, ms_b1, msc);
    hipLaunchKernelGGL(pair_mfma, dim3(1024, 8), dim3(512), pair_lds, stream,
                       embb, Wfrag16, H, spk_proj, bkt_proj, sp_b0, sp_W1, spk, slow0, slow1);
    hipLaunchKernelGGL(softmax_loss, dim3(1024), dim3(128), 0, stream,
                       slow0, slow1, msc, sp_b1, clus, out, lossp);
    hipLaunchKernelGGL(loss_sum, dim3(1), dim3(256), 0, stream, lossp, out);
}

// Round 8
// 347.919 us; speedup vs baseline: 1.1584x; 1.0369x over previous
//
#include <hip/hip_runtime.h>
#include <math.h>

// Problem constants (B=1)
#define MM 1024
#define DD 512
#define CC 128
#define LDSR 516   // A row stride in ushorts: 1032 B = 258 dw ≡ 2 (mod 32).
                   // b64 reads/8B stores: uniform 4 accesses/bank/wave = 2/phase -> free.

// ws layout (floats):
//  H[1024][3072]      @ 0        (0..1023 ms-hidden, 1024.. src_proj, 2048.. ant_proj)
//  slow[1024][128]    @ 3145728
//  spk_proj[2][1024]  @ 3276800
//  bkt_proj[10][1024] @ 3278848
//  ms[1024]           @ 3289088
//  lossp[1024]        @ 3290112
//  embb bf16[1024][512]  @ 3291136
//  Wall bf16[4096][512]  @ 3553280
//    rows [0,1024)=ms_W0^T, [1024,2048)=W_src^T, [2048,3072)=W_ant^T
//    region [3072,4096) reused as WfragP (pair-contiguous 16x16 fragment-major W_prod):
//      [g2:32][s:16][j:2][lane:64][8] bf16, g2 = wave*4+ft, tile t16 = wave*8+ft*2+j
//      element (f = t16*16 + (lane&15), k = s*32 + ((lane>>4)&3)*8 + e)
//      at byte g2*32768 + s*2048 + j*1024 + lane*16 + e*2
//      -> in-kernel loads: imm-foldable offsets (b0/b1 at +0/+1024, s-stride 2048)

typedef __attribute__((ext_vector_type(8))) short bf16x8;
typedef __attribute__((ext_vector_type(4), aligned(8))) short bf16x4a;
typedef __attribute__((ext_vector_type(4))) float f32x4;

__device__ __forceinline__ ushort bf16_rn(float x) {
    uint u = __float_as_uint(x);
    uint r = u + 0x7fffu + ((u >> 16) & 1u);
    return (ushort)(r >> 16);
}
__device__ __forceinline__ float bf16_to_f(ushort u) {
    return __uint_as_float(((uint)u) << 16);
}
__device__ __forceinline__ bf16x8 ld_lds16(const ushort* p) {   // two ds_read_b64 (8B-aligned)
    bf16x4a lo = *(const bf16x4a*)p;
    bf16x4a hi = *(const bf16x4a*)(p + 4);
    return __builtin_shufflevector(lo, hi, 0, 1, 2, 3, 4, 5, 6, 7);
}

// ---------------- prep: emb fp32 -> bf16
__global__ __launch_bounds__(256) void prep_emb(const float* __restrict__ emb,
                                                ushort* __restrict__ embb)
{
    int i = blockIdx.x * 256 + threadIdx.x;
    float2 v = ((const float2*)emb)[i];
    ushort2 o;
    o.x = bf16_rn(v.x);
    o.y = bf16_rn(v.y);
    ((ushort2*)embb)[i] = o;
}

// ---------------- prep: transpose+convert W0 blocks 0..2 -> Wall[3072 n][512 k] bf16
__global__ __launch_bounds__(256) void prep_wall(const float* __restrict__ ms_W0,
                                                 const float* __restrict__ sp_W0,
                                                 ushort* __restrict__ Wall)
{
    __shared__ float t[64][65];
    const int k0 = blockIdx.x * 64;   // 8
    const int n0 = blockIdx.y * 64;   // 48
    const int g = n0 >> 10;
    const float* src = (g == 0) ? ms_W0 : (sp_W0 + (size_t)(g - 1) * 512 * 1024);
    const int col0 = n0 & 1023;
    const int tr = threadIdx.x >> 6, tc = threadIdx.x & 63;
#pragma unroll
    for (int i = 0; i < 16; ++i) {
        int k = tr + i * 4;
        t[k][tc] = src[(size_t)(k0 + k) * 1024 + col0 + tc];
    }
    __syncthreads();
    const int f = threadIdx.x >> 2;
    const int c4 = threadIdx.x & 3;
    ushort tmp[16];
#pragma unroll
    for (int j = 0; j < 16; ++j) tmp[j] = bf16_rn(t[c4 * 16 + j][f]);
    uint4* dst = (uint4*)(Wall + (size_t)(n0 + f) * 512 + k0 + c4 * 16);
    dst[0] = *(uint4*)&tmp[0];
    dst[1] = *(uint4*)&tmp[8];
}

// ---------------- prep: W_prod [k=512][f=1024] -> pair-contiguous 16x16 fragment-major
__global__ __launch_bounds__(64) void prep_wfragP(const float* __restrict__ W,
                                                  ushort* __restrict__ dst_frag)
{
    const int bid = blockIdx.x;           // 0..1023 = g2*32 + s*2 + j
    const int l = threadIdx.x;            // 0..63
    const int g2 = bid >> 5, s = (bid >> 1) & 15, j = bid & 1;
    const int wave = g2 >> 2, ft = g2 & 3;
    const int t16 = wave * 8 + ft * 2 + j;
    const int f = t16 * 16 + (l & 15);
    const int kb = s * 32 + ((l >> 4) & 3) * 8;
    ushort tmp[8];
#pragma unroll
    for (int e = 0; e < 8; ++e) tmp[e] = bf16_rn(W[(size_t)(kb + e) * 1024 + f]);
    uint4* dst = (uint4*)(dst_frag + (size_t)bid * 512 + l * 8);
    *dst = *(uint4*)&tmp[0];
}

// ---------------- H = emb @ [ms_W0 | W_src | W_ant] via MFMA (1024x512x3072)
__global__ __launch_bounds__(256) void gemm_h_mfma(
    const ushort* __restrict__ embb, const ushort* __restrict__ Wall,
    float* __restrict__ H)
{
    const int n0 = blockIdx.x * 128;  // 24
    const int m0 = blockIdx.y * 128;  // 8
    const int lane = threadIdx.x & 63, wave = threadIdx.x >> 6;
    const int wx = wave & 1, wy = wave >> 1;
    const int l15 = lane & 15, lq = lane >> 4;

    const ushort* arow[4];
#pragma unroll
    for (int mi = 0; mi < 4; ++mi)
        arow[mi] = embb + (size_t)(m0 + wy * 64 + mi * 16 + l15) * 512;
    const ushort* brow[4];
#pragma unroll
    for (int ni = 0; ni < 4; ++ni)
        brow[ni] = Wall + (size_t)(n0 + wx * 64 + ni * 16 + l15) * 512;

    f32x4 acc[4][4];
#pragma unroll
    for (int i = 0; i < 4; ++i)
#pragma unroll
        for (int j = 0; j < 4; ++j) acc[i][j] = (f32x4)0.f;

    for (int kt = 0; kt < 512; kt += 32) {
        const int ko = kt + lq * 8;
        bf16x8 av[4], bv[4];
#pragma unroll
        for (int mi = 0; mi < 4; ++mi) av[mi] = *(const bf16x8*)(arow[mi] + ko);
#pragma unroll
        for (int ni = 0; ni < 4; ++ni) bv[ni] = *(const bf16x8*)(brow[ni] + ko);
#pragma unroll
        for (int mi = 0; mi < 4; ++mi)
#pragma unroll
            for (int ni = 0; ni < 4; ++ni)
                acc[mi][ni] = __builtin_amdgcn_mfma_f32_16x16x32_bf16(av[mi], bv[ni], acc[mi][ni], 0, 0, 0);
    }
#pragma unroll
    for (int mi = 0; mi < 4; ++mi)
#pragma unroll
        for (int r = 0; r < 4; ++r) {
            int mrow = m0 + wy * 64 + mi * 16 + lq * 4 + r;
#pragma unroll
            for (int ni = 0; ni < 4; ++ni)
                H[(size_t)mrow * 3072 + n0 + wx * 64 + ni * 16 + l15] = acc[mi][ni][r];
        }
}

// ---------------- small projections
__global__ void small_proj(const float* __restrict__ speaker_emb,
                           const float* __restrict__ bucket_emb,
                           const float* __restrict__ sp_W0,
                           float* __restrict__ spk_proj, float* __restrict__ bkt_proj)
{
    int r = blockIdx.x; // 0..11
    const float* e; const float* W; float* out;
    if (r < 2) { e = speaker_emb + r * 20; W = sp_W0 + (size_t)1536 * 1024; out = spk_proj + r * 1024; }
    else       { e = bucket_emb + (r - 2) * 20; W = sp_W0 + (size_t)1556 * 1024; out = bkt_proj + (r - 2) * 1024; }
    float ek[20];
#pragma unroll
    for (int k = 0; k < 20; ++k) ek[k] = e[k];
    for (int f = threadIdx.x; f < 1024; f += blockDim.x) {
        float s = 0.f;
#pragma unroll
        for (int k = 0; k < 20; ++k) s = fmaf(ek[k], W[(size_t)k * 1024 + f], s);
        out[f] = s;
    }
}

// ---------------- mention scores
__global__ __launch_bounds__(256) void mention_score(
    const float* __restrict__ H, const float* __restrict__ ms_b0,
    const float* __restrict__ ms_W1, const float* __restrict__ ms_b1,
    float* __restrict__ ms)
{
    int m = blockIdx.x;
    float v = 0.f;
    for (int f = threadIdx.x; f < 1024; f += 256) {
        float h = H[(size_t)m * 3072 + f] + ms_b0[f];
        v += fmaxf(h, 0.f) * ms_W1[f];
    }
#pragma unroll
    for (int o = 1; o < 64; o <<= 1) v += __shfl_xor(v, o);
    __shared__ float sm[4];
    if ((threadIdx.x & 63) == 0) sm[threadIdx.x >> 6] = v;
    __syncthreads();
    if (threadIdx.x == 0) ms[m] = sm[0] + sm[1] + sm[2] + sm[3] + ms_b1[0];
}

// ---------------- pair scorer v9: v8 skeleton + 4 VALU/overhead cuts.
// Grid (1024 m, 4 cq); 512 thr / 8 waves; A-tile 32c x 512k (34.3 KB) -> 4 blocks/CU,
// launch_bounds(512,8) -> 8 waves/SIMD. Wave covers 32c x 128f via ft=0..3 loop
// (fh merged into block: halves A-build + block count vs v8). Per ft: 16-step k-loop
// (16x16x32 MFMA, acc[ct][fi] = 16 AGPR) + epilogue accumulating into sacc[2][4]
// registers; ONE 4-shfl reduce per (ct,reg) after the ft loop (was 4x). All epilogue
// gathers use 32-bit indices off uniform bases (saddr+voffset form, no size_t mults).
// B loads from pair-contiguous WfragP: imm-foldable offsets.
__global__ __launch_bounds__(512, 8) void pair_mfma(
    const ushort* __restrict__ embb, const ushort* __restrict__ WfragP,
    const float* __restrict__ H, const float* __restrict__ spk_proj,
    const float* __restrict__ bkt_proj, const float* __restrict__ sp_b0,
    const float* __restrict__ sp_W1, const int* __restrict__ speaker,
    float* __restrict__ slow)
{
    extern __shared__ ushort Alds[];                  // 32*LDSR ushorts
    float* red = (float*)(Alds + 32 * LDSR);          // 8*32 floats
    int* meta_ss = (int*)(red + 8 * 32);              // 32 ints
    int* meta_bk = meta_ss + 32;                      // 32 ints
    const int m = blockIdx.x;
    const int cq = blockIdx.y;                        // c-quarter
    const int cbase = cq * 32;
    const int tid = threadIdx.x;
    const int spk_m = speaker[m];

    // ---- build A[c][k] = bf16(em[k]*ea[k]) in LDS + per-c metadata (32 rows)
    // lane->row c = tid&31: 8B stores uniform 4 accesses/bank/wave = free (0 measured).
    {
        const int c = tid & 31;
        const int kh = (tid >> 5) * 32;               // 16 chunks of 32 ushorts
        int a = m - 1 - (cbase + c); if (a < 0) a = 0;
        const ushort* ea = embb + (size_t)a * 512 + kh;
        const ushort* em = embb + (size_t)m * 512 + kh;
        ushort* dst = Alds + c * LDSR + kh;
#pragma unroll
        for (int j = 0; j < 32; j += 8) {
            bf16x8 va = *(const bf16x8*)(ea + j);
            bf16x8 vm = *(const bf16x8*)(em + j);
            uint pr[4];
#pragma unroll
            for (int p = 0; p < 4; ++p) {
                float q0 = bf16_to_f((ushort)va[2 * p])     * bf16_to_f((ushort)vm[2 * p]);
                float q1 = bf16_to_f((ushort)va[2 * p + 1]) * bf16_to_f((ushort)vm[2 * p + 1]);
                pr[p] = __builtin_amdgcn_perm(__float_as_uint(q1), __float_as_uint(q0), 0x07060302u);
            }
            *(uint2*)(dst + j)     = *(uint2*)&pr[0];   // 8B stores (rows are 8B-aligned)
            *(uint2*)(dst + j + 4) = *(uint2*)&pr[2];
        }
        if (tid < 32) {                               // c == tid
            meta_ss[c] = (speaker[a] == spk_m) ? 1 : 0;
            int off = cbase + c + 1;                  // 1..128
            int bk;
            if (off <= 4) bk = off;
            else { bk = 31 - __clz(off) + 3; if (bk > 9) bk = 9; }
            meta_bk[c] = bk;
        }
    }
    __syncthreads();

    const int lane = tid & 63;
    const int wave = __builtin_amdgcn_readfirstlane(tid >> 6);   // 0..7, wave-uniform
    const int l15 = lane & 15, lq = lane >> 4;
    const ushort* ab0 = Alds + l15 * LDSR + lq * 8;   // ct=0; ct=1 at +16*LDSR

    // uniform bases for 32-bit-indexed epilogue gathers
    const float* Hsrc = H + m * 3072 + 1024;          // block-uniform
    const float* Hant = H + 2048;

    float sacc[2][4];
#pragma unroll
    for (int ct = 0; ct < 2; ++ct)
#pragma unroll
        for (int r = 0; r < 4; ++r) sacc[ct][r] = 0.f;

#pragma unroll 1
    for (int ft = 0; ft < 4; ++ft) {
        const int f0a = wave * 128 + ft * 32;
        // B: pair-contiguous; b0/b1 at +0/+1024B, s-stride 2048B (imm-foldable)
        const ushort* bb = WfragP + (size_t)(wave * 4 + ft) * 16384 + (size_t)lane * 8;
        f32x4 acc[2][2];
#pragma unroll
        for (int i = 0; i < 2; ++i)
#pragma unroll
            for (int j = 0; j < 2; ++j) acc[i][j] = (f32x4)0.f;

#pragma unroll 4
        for (int s = 0; s < 16; ++s) {
            bf16x8 b0 = *(const bf16x8*)(bb + s * 1024);
            bf16x8 b1 = *(const bf16x8*)(bb + s * 1024 + 512);
            bf16x8 a0 = ld_lds16(ab0 + s * 32);
            bf16x8 a1 = ld_lds16(ab0 + 16 * LDSR + s * 32);
            __builtin_amdgcn_s_setprio(1);
            acc[0][0] = __builtin_amdgcn_mfma_f32_16x16x32_bf16(a0, b0, acc[0][0], 0, 0, 0);
            acc[0][1] = __builtin_amdgcn_mfma_f32_16x16x32_bf16(a0, b1, acc[0][1], 0, 0, 0);
            acc[1][0] = __builtin_amdgcn_mfma_f32_16x16x32_bf16(a1, b0, acc[1][0], 0, 0, 0);
            acc[1][1] = __builtin_amdgcn_mfma_f32_16x16x32_bf16(a1, b1, acc[1][1], 0, 0, 0);
            __builtin_amdgcn_s_setprio(0);
        }

        // ---- per-ft epilogue: fold into sacc (reduce deferred past the ft loop)
        float srcb[2], w1v[2], sp0v[2], sp1v[2];
#pragma unroll
        for (int fi = 0; fi < 2; ++fi) {
            const int fcol = f0a + fi * 16 + l15;
            srcb[fi] = Hsrc[fcol] + sp_b0[fcol];
            w1v[fi]  = sp_W1[fcol];
            sp0v[fi] = spk_proj[fcol];
            sp1v[fi] = spk_proj[1024 + fcol];
        }
        // C/D 16x16 layout: col(f) = lane&15, row(c) = lq*4 + reg
#pragma unroll
        for (int ct = 0; ct < 2; ++ct) {
#pragma unroll
            for (int reg = 0; reg < 4; ++reg) {
                const int cl = ct * 16 + lq * 4 + reg;        // 0..31 local
                int a = m - 1 - (cbase + cl); if (a < 0) a = 0;
                const int ss = meta_ss[cl];
                const int aidx = a * 3072;                    // 32-bit
                const int bidx = meta_bk[cl] << 10;           // 32-bit
                float s = sacc[ct][reg];
#pragma unroll
                for (int fi = 0; fi < 2; ++fi) {
                    const int fcol = f0a + fi * 16 + l15;
                    float bval = bkt_proj[bidx + fcol];
                    float pre = acc[ct][fi][reg] + srcb[fi] + Hant[aidx + fcol]
                              + (ss ? sp1v[fi] : sp0v[fi]) + bval;
                    s += fmaxf(pre, 0.f) * w1v[fi];
                }
                sacc[ct][reg] = s;
            }
        }
    }

    // ---- single deferred reduce per (ct,reg): 8 chains instead of 32
#pragma unroll
    for (int ct = 0; ct < 2; ++ct) {
#pragma unroll
        for (int reg = 0; reg < 4; ++reg) {
            float s = sacc[ct][reg];
            s += __shfl_xor(s, 1); s += __shfl_xor(s, 2);
            s += __shfl_xor(s, 4); s += __shfl_xor(s, 8);
            if (l15 == 0) red[wave * 32 + ct * 16 + lq * 4 + reg] = s;
        }
    }
    __syncthreads();
    if (tid < 32) {
        float s = 0.f;
#pragma unroll
        for (int i = 0; i < 8; ++i) s += red[i * 32 + tid];
        slow[m * 128 + cbase + tid] = s;                      // full f-sum: single buffer
    }
}

// ---------------- softmax + per-mention loss
__device__ __forceinline__ float bsum2(float v, float* sm) {
#pragma unroll
    for (int o = 1; o < 64; o <<= 1) v += __shfl_xor(v, o);
    __syncthreads();
    if ((threadIdx.x & 63) == 0) sm[threadIdx.x >> 6] = v;
    __syncthreads();
    return sm[0] + sm[1];
}
__device__ __forceinline__ float bmax2(float v, float* sm) {
#pragma unroll
    for (int o = 1; o < 64; o <<= 1) v = fmaxf(v, __shfl_xor(v, o));
    __syncthreads();
    if ((threadIdx.x & 63) == 0) sm[threadIdx.x >> 6] = v;
    __syncthreads();
    return fmaxf(sm[0], sm[1]);
}

__global__ __launch_bounds__(128) void softmax_loss(
    const float* __restrict__ slow, const float* __restrict__ ms,
    const float* __restrict__ sp_b1, const int* __restrict__ cluster,
    float* __restrict__ out, float* __restrict__ loss_partial)
{
    const int m = blockIdx.x, c = threadIdx.x;
    __shared__ float sm[2];
    const int raw = m - 1 - c;
    const bool maskv = raw >= 0;
    const int a = maskv ? raw : 0;
    float score = slow[(size_t)m * 128 + c] + sp_b1[0] + ms[m] + ms[a];
    if (!maskv) score = -INFINITY;

    float mx = fmaxf(bmax2(score, sm), 0.f);
    float e = expf(score - mx);
    float e0 = expf(0.f - mx);
    float sum = bsum2(e, sm) + e0;
    float p = e / sum, p0 = e0 / sum;
    const float eps = 1e-6f;
    p  = fminf(fmaxf(p,  eps), 1.f - eps);
    p0 = fminf(fmaxf(p0, eps), 1.f - eps);
    float sum2 = bsum2(p, sm) + p0;
    p /= sum2; p0 /= sum2;
    out[(size_t)m * 129 + 1 + c] = p;
    if (c == 0) out[(size_t)m * 129] = p0;

    const int cid = cluster[m];
    const bool lbl = maskv && (cid > 0) && (cluster[a] == cid);
    float anyc = bsum2(lbl ? 1.f : 0.f, sm);
    float lsum = bsum2(lbl ? -logf(p) : 0.f, sm);
    if (c == 0) {
        if (anyc == 0.f) lsum += -logf(p0);
        loss_partial[m] = lsum;
    }
}

__global__ void loss_sum(const float* __restrict__ lp, float* __restrict__ out) {
    float v = 0.f;
    for (int i = threadIdx.x; i < 1024; i += 256) v += lp[i];
#pragma unroll
    for (int o = 1; o < 64; o <<= 1) v += __shfl_xor(v, o);
    __shared__ float sm[4];
    if ((threadIdx.x & 63) == 0) sm[threadIdx.x >> 6] = v;
    __syncthreads();
    if (threadIdx.x == 0) out[(size_t)1024 * 129] = sm[0] + sm[1] + sm[2] + sm[3];
}

extern "C" void kernel_launch(void* const* d_in, const int* in_sizes, int n_in,
                              void* d_out, int out_size, void* d_ws, size_t ws_size,
                              hipStream_t stream)
{
    const float* emb   = (const float*)d_in[0];
    const int*   clus  = (const int*)  d_in[1];
    const int*   spk   = (const int*)  d_in[2];
    const float* ms_W0 = (const float*)d_in[3];
    const float* ms_b0 = (const float*)d_in[4];
    const float* ms_W1 = (const float*)d_in[5];
    const float* ms_b1 = (const float*)d_in[6];
    const float* sp_W0 = (const float*)d_in[7];
    const float* sp_b0 = (const float*)d_in[8];
    const float* sp_W1 = (const float*)d_in[9];
    const float* sp_b1 = (const float*)d_in[10];
    const float* spke  = (const float*)d_in[11];
    const float* bkte  = (const float*)d_in[12];

    float* ws = (float*)d_ws;
    float* H        = ws;
    float* slow     = ws + 3145728;
    float* spk_proj = ws + 3276800;
    float* bkt_proj = ws + 3278848;
    float* msc      = ws + 3289088;
    float* lossp    = ws + 3290112;
    ushort* embb    = (ushort*)(ws + 3291136);
    ushort* Wall    = (ushort*)(ws + 3553280);
    ushort* WfragP  = Wall + (size_t)3072 * 512;   // reuse W_prod region, pair-frag-major
    float* out = (float*)d_out;

    const int pair_lds = 32 * LDSR * 2 + 8 * 32 * 4 + 2 * 32 * 4;   // 34304 B

    static bool attr_set = false;
    if (!attr_set) {
        hipFuncSetAttribute((const void*)&pair_mfma,
                            hipFuncAttributeMaxDynamicSharedMemorySize,
                            pair_lds);
        attr_set = true;
    }

    hipLaunchKernelGGL(prep_emb, dim3(1024), dim3(256), 0, stream, emb, embb);
    hipLaunchKernelGGL(prep_wall, dim3(8, 48), dim3(256), 0, stream, ms_W0, sp_W0, Wall);
    hipLaunchKernelGGL(prep_wfragP, dim3(1024), dim3(64), 0, stream,
                       sp_W0 + (size_t)1024 * 1024, WfragP);    // W_prod
    hipLaunchKernelGGL(gemm_h_mfma, dim3(24, 8), dim3(256), 0, stream, embb, Wall, H);
    hipLaunchKernelGGL(small_proj, dim3(12), dim3(256), 0, stream, spke, bkte, sp_W0, spk_proj, bkt_proj);
    hipLaunchKernelGGL(mention_score, dim3(1024), dim3(256), 0, stream, H, ms_b0, ms_W1, ms_b1, msc);
    hipLaunchKernelGGL(pair_mfma, dim3(1024, 4), dim3(512), pair_lds, stream,
                       embb, WfragP, H, spk_proj, bkt_proj, sp_b0, sp_W1, spk, slow);
    hipLaunchKernelGGL(softmax_loss, dim3(1024), dim3(128), 0, stream,
                       slow, msc, sp_b1, clus, out, lossp);
    hipLaunchKernelGGL(loss_sum, dim3(1), dim3(256), 0, stream, lossp, out);
}

// Round 9
// 329.176 us; speedup vs baseline: 1.2243x; 1.0569x over previous
//
#include <hip/hip_runtime.h>
#include <math.h>

// Problem constants (B=1)
#define MM 1024
#define DD 512
#define CC 128
#define LDSR 516   // A row stride in ushorts: 1032 B = 258 dw ≡ 2 (mod 32).
                   // b64 reads/8B stores: uniform 4 accesses/bank/wave = 2/phase -> free.

// ws layout (floats):
//  H[1024][3072]      @ 0        (0..1023 unused now; 1024.. src_proj, 2048.. ant_proj)
//  slow[1024][128]    @ 3145728
//  spk_proj[2][1024]  @ 3276800
//  bkt_proj[10][1024] @ 3278848
//  ms[1024]           @ 3289088   (raw dot partials, atomically accumulated; no b1)
//  lossp[1024]        @ 3290112
//  embb bf16[1024][512]  @ 3291136
//  Wall bf16[4096][512]  @ 3553280
//    rows [0,1024)=ms_W0^T, [1024,2048)=W_src^T, [2048,3072)=W_ant^T
//    region [3072,4096) reused as WfragP (pair-contiguous 16x16 fragment-major W_prod):
//      [g2:32][s:16][j:2][lane:64][8] bf16, g2 = wave*4+ft, tile t16 = wave*8+ft*2+j
//      element (f = t16*16 + (lane&15), k = s*32 + ((lane>>4)&3)*8 + e)
//      at byte g2*32768 + s*2048 + j*1024 + lane*16 + e*2

typedef __attribute__((ext_vector_type(8))) short bf16x8;
typedef __attribute__((ext_vector_type(4), aligned(8))) short bf16x4a;
typedef __attribute__((ext_vector_type(4))) float f32x4;

__device__ __forceinline__ ushort bf16_rn(float x) {
    uint u = __float_as_uint(x);
    uint r = u + 0x7fffu + ((u >> 16) & 1u);
    return (ushort)(r >> 16);
}
__device__ __forceinline__ float bf16_to_f(ushort u) {
    return __uint_as_float(((uint)u) << 16);
}
__device__ __forceinline__ bf16x8 ld_lds16(const ushort* p) {   // two ds_read_b64 (8B-aligned)
    bf16x4a lo = *(const bf16x4a*)p;
    bf16x4a hi = *(const bf16x4a*)(p + 4);
    return __builtin_shufflevector(lo, hi, 0, 1, 2, 3, 4, 5, 6, 7);
}

// ---------------- prep_all: emb->bf16 | Wall transpose | WfragP | small projections
// grid ranges: [0,1024) emb; [1024,1408) wall; [1408,1664) wfragP; [1664,1676) small_proj
__global__ __launch_bounds__(256) void prep_all(
    const float* __restrict__ emb, ushort* __restrict__ embb,
    const float* __restrict__ ms_W0, const float* __restrict__ sp_W0,
    ushort* __restrict__ Wall, ushort* __restrict__ WfragP,
    const float* __restrict__ speaker_emb, const float* __restrict__ bucket_emb,
    float* __restrict__ spk_proj, float* __restrict__ bkt_proj)
{
    const int bid = blockIdx.x;
    const int tid = threadIdx.x;

    if (bid < 1024) {                               // ---- prep_emb
        int i = bid * 256 + tid;
        float2 v = ((const float2*)emb)[i];
        ushort2 o;
        o.x = bf16_rn(v.x);
        o.y = bf16_rn(v.y);
        ((ushort2*)embb)[i] = o;
        return;
    }
    if (bid < 1408) {                               // ---- prep_wall
        __shared__ float t[64][65];
        const int r = bid - 1024;                   // 0..383
        const int k0 = (r & 7) * 64;
        const int n0 = (r >> 3) * 64;
        const int g = n0 >> 10;
        const float* src = (g == 0) ? ms_W0 : (sp_W0 + (size_t)(g - 1) * 512 * 1024);
        const int col0 = n0 & 1023;
        const int tr = tid >> 6, tc = tid & 63;
#pragma unroll
        for (int i = 0; i < 16; ++i) {
            int k = tr + i * 4;
            t[k][tc] = src[(size_t)(k0 + k) * 1024 + col0 + tc];
        }
        __syncthreads();
        const int f = tid >> 2;
        const int c4 = tid & 3;
        ushort tmp[16];
#pragma unroll
        for (int j = 0; j < 16; ++j) tmp[j] = bf16_rn(t[c4 * 16 + j][f]);
        uint4* dst = (uint4*)(Wall + (size_t)(n0 + f) * 512 + k0 + c4 * 16);
        dst[0] = *(uint4*)&tmp[0];
        dst[1] = *(uint4*)&tmp[8];
        return;
    }
    if (bid < 1664) {                               // ---- prep_wfragP (4 bids per block)
        const int b4 = (bid - 1408) * 4 + (tid >> 6);   // 0..1023 = g2*32 + s*2 + j
        const int l = tid & 63;
        const int g2 = b4 >> 5, s = (b4 >> 1) & 15, j = b4 & 1;
        const int wv = g2 >> 2, ft = g2 & 3;
        const int t16 = wv * 8 + ft * 2 + j;
        const int f = t16 * 16 + (l & 15);
        const int kb = s * 32 + ((l >> 4) & 3) * 8;
        const float* W = sp_W0 + (size_t)1024 * 1024;   // W_prod [k=512][f=1024]
        ushort tmp[8];
#pragma unroll
        for (int e = 0; e < 8; ++e) tmp[e] = bf16_rn(W[(size_t)(kb + e) * 1024 + f]);
        uint4* dst = (uint4*)(WfragP + (size_t)b4 * 512 + l * 8);
        *dst = *(uint4*)&tmp[0];
        return;
    }
    {                                               // ---- small_proj
        const int r = bid - 1664;                   // 0..11
        const float* e; const float* W; float* out;
        if (r < 2) { e = speaker_emb + r * 20; W = sp_W0 + (size_t)1536 * 1024; out = spk_proj + r * 1024; }
        else       { e = bucket_emb + (r - 2) * 20; W = sp_W0 + (size_t)1556 * 1024; out = bkt_proj + (r - 2) * 1024; }
        float ek[20];
#pragma unroll
        for (int k = 0; k < 20; ++k) ek[k] = e[k];
        for (int f = tid; f < 1024; f += 256) {
            float s = 0.f;
#pragma unroll
            for (int k = 0; k < 20; ++k) s = fmaf(ek[k], W[(size_t)k * 1024 + f], s);
            out[f] = s;
        }
        return;
    }
}

// ---------------- H = emb @ [ms_W0 | W_src | W_ant] via MFMA, with the ms-hidden
// region (n<1024) consumed in-register: partial Σ relu(h+b0)·W1 -> atomicAdd(ms),
// and NOT stored to H (saves 4 MB write + 4 MB read + the mention_score kernel).
__global__ __launch_bounds__(256) void gemm_h_ms(
    const ushort* __restrict__ embb, const ushort* __restrict__ Wall,
    const float* __restrict__ ms_b0, const float* __restrict__ ms_W1,
    float* __restrict__ H, float* __restrict__ ms)
{
    const int n0 = blockIdx.x * 128;  // 24
    const int m0 = blockIdx.y * 128;  // 8
    const int lane = threadIdx.x & 63, wave = threadIdx.x >> 6;
    const int wx = wave & 1, wy = wave >> 1;
    const int l15 = lane & 15, lq = lane >> 4;

    const ushort* arow[4];
#pragma unroll
    for (int mi = 0; mi < 4; ++mi)
        arow[mi] = embb + (size_t)(m0 + wy * 64 + mi * 16 + l15) * 512;
    const ushort* brow[4];
#pragma unroll
    for (int ni = 0; ni < 4; ++ni)
        brow[ni] = Wall + (size_t)(n0 + wx * 64 + ni * 16 + l15) * 512;

    f32x4 acc[4][4];
#pragma unroll
    for (int i = 0; i < 4; ++i)
#pragma unroll
        for (int j = 0; j < 4; ++j) acc[i][j] = (f32x4)0.f;

    for (int kt = 0; kt < 512; kt += 32) {
        const int ko = kt + lq * 8;
        bf16x8 av[4], bv[4];
#pragma unroll
        for (int mi = 0; mi < 4; ++mi) av[mi] = *(const bf16x8*)(arow[mi] + ko);
#pragma unroll
        for (int ni = 0; ni < 4; ++ni) bv[ni] = *(const bf16x8*)(brow[ni] + ko);
#pragma unroll
        for (int mi = 0; mi < 4; ++mi)
#pragma unroll
            for (int ni = 0; ni < 4; ++ni)
                acc[mi][ni] = __builtin_amdgcn_mfma_f32_16x16x32_bf16(av[mi], bv[ni], acc[mi][ni], 0, 0, 0);
    }

    if (n0 < 1024) {
        // fused mention-score partial: cols n0+wx*64+ni*16+l15
        float b0v[4], w1v[4];
#pragma unroll
        for (int ni = 0; ni < 4; ++ni) {
            const int col = n0 + wx * 64 + ni * 16 + l15;
            b0v[ni] = ms_b0[col];
            w1v[ni] = ms_W1[col];
        }
#pragma unroll
        for (int mi = 0; mi < 4; ++mi)
#pragma unroll
            for (int r = 0; r < 4; ++r) {
                float s = 0.f;
#pragma unroll
                for (int ni = 0; ni < 4; ++ni)
                    s += fmaxf(acc[mi][ni][r] + b0v[ni], 0.f) * w1v[ni];
                // reduce across l15 (lane bits 0..3)
                s += __shfl_xor(s, 1); s += __shfl_xor(s, 2);
                s += __shfl_xor(s, 4); s += __shfl_xor(s, 8);
                if (l15 == 0) {
                    const int mrow = m0 + wy * 64 + mi * 16 + lq * 4 + r;
                    atomicAdd(&ms[mrow], s);
                }
            }
    } else {
#pragma unroll
        for (int mi = 0; mi < 4; ++mi)
#pragma unroll
            for (int r = 0; r < 4; ++r) {
                int mrow = m0 + wy * 64 + mi * 16 + lq * 4 + r;
#pragma unroll
                for (int ni = 0; ni < 4; ++ni)
                    H[(size_t)mrow * 3072 + n0 + wx * 64 + ni * 16 + l15] = acc[mi][ni][r];
            }
    }
}

// ---------------- pair scorer v9 (unchanged from r8: 238 µs, Occ 85%, 0 conflicts)
__global__ __launch_bounds__(512, 8) void pair_mfma(
    const ushort* __restrict__ embb, const ushort* __restrict__ WfragP,
    const float* __restrict__ H, const float* __restrict__ spk_proj,
    const float* __restrict__ bkt_proj, const float* __restrict__ sp_b0,
    const float* __restrict__ sp_W1, const int* __restrict__ speaker,
    float* __restrict__ slow)
{
    extern __shared__ ushort Alds[];                  // 32*LDSR ushorts
    float* red = (float*)(Alds + 32 * LDSR);          // 8*32 floats
    int* meta_ss = (int*)(red + 8 * 32);              // 32 ints
    int* meta_bk = meta_ss + 32;                      // 32 ints
    const int m = blockIdx.x;
    const int cq = blockIdx.y;                        // c-quarter
    const int cbase = cq * 32;
    const int tid = threadIdx.x;
    const int spk_m = speaker[m];

    // ---- build A[c][k] = bf16(em[k]*ea[k]) in LDS + per-c metadata (32 rows)
    {
        const int c = tid & 31;
        const int kh = (tid >> 5) * 32;               // 16 chunks of 32 ushorts
        int a = m - 1 - (cbase + c); if (a < 0) a = 0;
        const ushort* ea = embb + (size_t)a * 512 + kh;
        const ushort* em = embb + (size_t)m * 512 + kh;
        ushort* dst = Alds + c * LDSR + kh;
#pragma unroll
        for (int j = 0; j < 32; j += 8) {
            bf16x8 va = *(const bf16x8*)(ea + j);
            bf16x8 vm = *(const bf16x8*)(em + j);
            uint pr[4];
#pragma unroll
            for (int p = 0; p < 4; ++p) {
                float q0 = bf16_to_f((ushort)va[2 * p])     * bf16_to_f((ushort)vm[2 * p]);
                float q1 = bf16_to_f((ushort)va[2 * p + 1]) * bf16_to_f((ushort)vm[2 * p + 1]);
                pr[p] = __builtin_amdgcn_perm(__float_as_uint(q1), __float_as_uint(q0), 0x07060302u);
            }
            *(uint2*)(dst + j)     = *(uint2*)&pr[0];   // 8B stores (rows are 8B-aligned)
            *(uint2*)(dst + j + 4) = *(uint2*)&pr[2];
        }
        if (tid < 32) {                               // c == tid
            meta_ss[c] = (speaker[a] == spk_m) ? 1 : 0;
            int off = cbase + c + 1;                  // 1..128
            int bk;
            if (off <= 4) bk = off;
            else { bk = 31 - __clz(off) + 3; if (bk > 9) bk = 9; }
            meta_bk[c] = bk;
        }
    }
    __syncthreads();

    const int lane = tid & 63;
    const int wave = __builtin_amdgcn_readfirstlane(tid >> 6);   // 0..7, wave-uniform
    const int l15 = lane & 15, lq = lane >> 4;
    const ushort* ab0 = Alds + l15 * LDSR + lq * 8;   // ct=0; ct=1 at +16*LDSR

    const float* Hsrc = H + m * 3072 + 1024;          // block-uniform
    const float* Hant = H + 2048;

    float sacc[2][4];
#pragma unroll
    for (int ct = 0; ct < 2; ++ct)
#pragma unroll
        for (int r = 0; r < 4; ++r) sacc[ct][r] = 0.f;

#pragma unroll 1
    for (int ft = 0; ft < 4; ++ft) {
        const int f0a = wave * 128 + ft * 32;
        const ushort* bb = WfragP + (size_t)(wave * 4 + ft) * 16384 + (size_t)lane * 8;
        f32x4 acc[2][2];
#pragma unroll
        for (int i = 0; i < 2; ++i)
#pragma unroll
            for (int j = 0; j < 2; ++j) acc[i][j] = (f32x4)0.f;

#pragma unroll 4
        for (int s = 0; s < 16; ++s) {
            bf16x8 b0 = *(const bf16x8*)(bb + s * 1024);
            bf16x8 b1 = *(const bf16x8*)(bb + s * 1024 + 512);
            bf16x8 a0 = ld_lds16(ab0 + s * 32);
            bf16x8 a1 = ld_lds16(ab0 + 16 * LDSR + s * 32);
            __builtin_amdgcn_s_setprio(1);
            acc[0][0] = __builtin_amdgcn_mfma_f32_16x16x32_bf16(a0, b0, acc[0][0], 0, 0, 0);
            acc[0][1] = __builtin_amdgcn_mfma_f32_16x16x32_bf16(a0, b1, acc[0][1], 0, 0, 0);
            acc[1][0] = __builtin_amdgcn_mfma_f32_16x16x32_bf16(a1, b0, acc[1][0], 0, 0, 0);
            acc[1][1] = __builtin_amdgcn_mfma_f32_16x16x32_bf16(a1, b1, acc[1][1], 0, 0, 0);
            __builtin_amdgcn_s_setprio(0);
        }

        float srcb[2], w1v[2], sp0v[2], sp1v[2];
#pragma unroll
        for (int fi = 0; fi < 2; ++fi) {
            const int fcol = f0a + fi * 16 + l15;
            srcb[fi] = Hsrc[fcol] + sp_b0[fcol];
            w1v[fi]  = sp_W1[fcol];
            sp0v[fi] = spk_proj[fcol];
            sp1v[fi] = spk_proj[1024 + fcol];
        }
#pragma unroll
        for (int ct = 0; ct < 2; ++ct) {
#pragma unroll
            for (int reg = 0; reg < 4; ++reg) {
                const int cl = ct * 16 + lq * 4 + reg;        // 0..31 local
                int a = m - 1 - (cbase + cl); if (a < 0) a = 0;
                const int ss = meta_ss[cl];
                const int aidx = a * 3072;                    // 32-bit
                const int bidx = meta_bk[cl] << 10;           // 32-bit
                float s = sacc[ct][reg];
#pragma unroll
                for (int fi = 0; fi < 2; ++fi) {
                    const int fcol = f0a + fi * 16 + l15;
                    float bval = bkt_proj[bidx + fcol];
                    float pre = acc[ct][fi][reg] + srcb[fi] + Hant[aidx + fcol]
                              + (ss ? sp1v[fi] : sp0v[fi]) + bval;
                    s += fmaxf(pre, 0.f) * w1v[fi];
                }
                sacc[ct][reg] = s;
            }
        }
    }

#pragma unroll
    for (int ct = 0; ct < 2; ++ct) {
#pragma unroll
        for (int reg = 0; reg < 4; ++reg) {
            float s = sacc[ct][reg];
            s += __shfl_xor(s, 1); s += __shfl_xor(s, 2);
            s += __shfl_xor(s, 4); s += __shfl_xor(s, 8);
            if (l15 == 0) red[wave * 32 + ct * 16 + lq * 4 + reg] = s;
        }
    }
    __syncthreads();
    if (tid < 32) {
        float s = 0.f;
#pragma unroll
        for (int i = 0; i < 8; ++i) s += red[i * 32 + tid];
        slow[m * 128 + cbase + tid] = s;
    }
}

// ---------------- softmax + per-mention loss (ms = raw dots; b1 added here, 2x)
__device__ __forceinline__ float bsum2(float v, float* sm) {
#pragma unroll
    for (int o = 1; o < 64; o <<= 1) v += __shfl_xor(v, o);
    __syncthreads();
    if ((threadIdx.x & 63) == 0) sm[threadIdx.x >> 6] = v;
    __syncthreads();
    return sm[0] + sm[1];
}
__device__ __forceinline__ float bmax2(float v, float* sm) {
#pragma unroll
    for (int o = 1; o < 64; o <<= 1) v = fmaxf(v, __shfl_xor(v, o));
    __syncthreads();
    if ((threadIdx.x & 63) == 0) sm[threadIdx.x >> 6] = v;
    __syncthreads();
    return fmaxf(sm[0], sm[1]);
}

__global__ __launch_bounds__(128) void softmax_loss(
    const float* __restrict__ slow, const float* __restrict__ ms,
    const float* __restrict__ ms_b1,
    const float* __restrict__ sp_b1, const int* __restrict__ cluster,
    float* __restrict__ out, float* __restrict__ loss_partial)
{
    const int m = blockIdx.x, c = threadIdx.x;
    __shared__ float sm[2];
    const int raw = m - 1 - c;
    const bool maskv = raw >= 0;
    const int a = maskv ? raw : 0;
    float score = slow[(size_t)m * 128 + c] + sp_b1[0]
                + ms[m] + ms[a] + 2.f * ms_b1[0];
    if (!maskv) score = -INFINITY;

    float mx = fmaxf(bmax2(score, sm), 0.f);
    float e = expf(score - mx);
    float e0 = expf(0.f - mx);
    float sum = bsum2(e, sm) + e0;
    float p = e / sum, p0 = e0 / sum;
    const float eps = 1e-6f;
    p  = fminf(fmaxf(p,  eps), 1.f - eps);
    p0 = fminf(fmaxf(p0, eps), 1.f - eps);
    float sum2 = bsum2(p, sm) + p0;
    p /= sum2; p0 /= sum2;
    out[(size_t)m * 129 + 1 + c] = p;
    if (c == 0) out[(size_t)m * 129] = p0;

    const int cid = cluster[m];
    const bool lbl = maskv && (cid > 0) && (cluster[a] == cid);
    float anyc = bsum2(lbl ? 1.f : 0.f, sm);
    float lsum = bsum2(lbl ? -logf(p) : 0.f, sm);
    if (c == 0) {
        if (anyc == 0.f) lsum += -logf(p0);
        loss_partial[m] = lsum;
    }
}

__global__ void loss_sum(const float* __restrict__ lp, float* __restrict__ out) {
    float v = 0.f;
    for (int i = threadIdx.x; i < 1024; i += 256) v += lp[i];
#pragma unroll
    for (int o = 1; o < 64; o <<= 1) v += __shfl_xor(v, o);
    __shared__ float sm[4];
    if ((threadIdx.x & 63) == 0) sm[threadIdx.x >> 6] = v;
    __syncthreads();
    if (threadIdx.x == 0) out[(size_t)1024 * 129] = sm[0] + sm[1] + sm[2] + sm[3];
}

extern "C" void kernel_launch(void* const* d_in, const int* in_sizes, int n_in,
                              void* d_out, int out_size, void* d_ws, size_t ws_size,
                              hipStream_t stream)
{
    const float* emb   = (const float*)d_in[0];
    const int*   clus  = (const int*)  d_in[1];
    const int*   spk   = (const int*)  d_in[2];
    const float* ms_W0 = (const float*)d_in[3];
    const float* ms_b0 = (const float*)d_in[4];
    const float* ms_W1 = (const float*)d_in[5];
    const float* ms_b1 = (const float*)d_in[6];
    const float* sp_W0 = (const float*)d_in[7];
    const float* sp_b0 = (const float*)d_in[8];
    const float* sp_W1 = (const float*)d_in[9];
    const float* sp_b1 = (const float*)d_in[10];
    const float* spke  = (const float*)d_in[11];
    const float* bkte  = (const float*)d_in[12];

    float* ws = (float*)d_ws;
    float* H        = ws;
    float* slow     = ws + 3145728;
    float* spk_proj = ws + 3276800;
    float* bkt_proj = ws + 3278848;
    float* msc      = ws + 3289088;
    float* lossp    = ws + 3290112;
    ushort* embb    = (ushort*)(ws + 3291136);
    ushort* Wall    = (ushort*)(ws + 3553280);
    ushort* WfragP  = Wall + (size_t)3072 * 512;   // reuse W_prod region, pair-frag-major
    float* out = (float*)d_out;

    const int pair_lds = 32 * LDSR * 2 + 8 * 32 * 4 + 2 * 32 * 4;   // 34304 B

    static bool attr_set = false;
    if (!attr_set) {
        hipFuncSetAttribute((const void*)&pair_mfma,
                            hipFuncAttributeMaxDynamicSharedMemorySize,
                            pair_lds);
        attr_set = true;
    }

    hipMemsetAsync(msc, 0, 1024 * sizeof(float), stream);
    hipLaunchKernelGGL(prep_all, dim3(1676), dim3(256), 0, stream,
                       emb, embb, ms_W0, sp_W0, Wall, WfragP,
                       spke, bkte, spk_proj, bkt_proj);
    hipLaunchKernelGGL(gemm_h_ms, dim3(24, 8), dim3(256), 0, stream,
                       embb, Wall, ms_b0, ms_W1, H, msc);
    hipLaunchKernelGGL(pair_mfma, dim3(1024, 4), dim3(512), pair_lds, stream,
                       embb, WfragP, H, spk_proj, bkt_proj, sp_b0, sp_W1, spk, slow);
    hipLaunchKernelGGL(softmax_loss, dim3(1024), dim3(128), 0, stream,
                       slow, msc, ms_b1, sp_b1, clus, out, lossp);
    hipLaunchKernelGGL(loss_sum, dim3(1), dim3(256), 0, stream, lossp, out);
}